// Round 8
// baseline (78.286 us; speedup 1.0000x reference)
//
#include <hip/hip_runtime.h>
#include <stdint.h>

#define TT 256
#define BB 2048
#define AA 18
#define NTB (TT * BB)
#define WPB 8          // waves per block; ONE timestep per wave
#define TPB 8          // timesteps per block
#define NTBLK 32       // TT / TPB
#define NBLK 1024      // NTBLK * 32 col-groups
#define LDST 65        // LDS row stride (floats), conflict-free
#define TILE (AA * LDST)   // 1170 floats per wave tile
#define LN2 0.69314718055994531f

// ws layout:
//   [0..255]   int counters: root at [0], gcnt[32] at [4..131] (memset to 0)
//   [256..)    part[NBLK*32] floats  (per-block 128B line: ent, sv, sp)
//   then       wsf[5][NTBLK][BB] composed tuples (1.25 MB)

__global__ __launch_bounds__(512) void fused_k(
    const float* __restrict__ policy,
    const float* __restrict__ behavior,
    const float* __restrict__ rewards,
    const float* __restrict__ values,
    const float* __restrict__ next_values,
    const int* __restrict__ actions,
    const void* __restrict__ done,
    float* __restrict__ part,
    float* __restrict__ wsf,
    int* __restrict__ root,
    int* __restrict__ gcnt,
    float* __restrict__ out)
{
    int tid = threadIdx.x;
    int lane = tid & 63;
    int w = tid >> 6;                 // wave 0..7 == local timestep
    int bid = blockIdx.x;
    int tb = bid >> 5;                // time-block 0..31
    int g = bid & 31;                 // col-group 0..31

    __shared__ float lpol[WPB][TILE]; // 37.4 KB, wave-private (reused for tuples)
    __shared__ float red[WPB][3];
    __shared__ int is_last;

    // --- per-wave done-layout detection (4KB scan, no barrier) ---
    const int* di = (const int*)done;
    int bad = 0;
#pragma unroll
    for (int i = 0; i < 16; ++i) {
        int v = di[lane + 64 * i];
        bad |= !(v == 0 || v == 1 || v == 0x3F800000);
    }
    bool bytelay = (__any(bad) != 0);

    int t = tb * TPB + w;
    int b = g * 64 + lane;
    int r = t * BB + b;

    // --- early scalar-array loads (issue before the gather needs them) ---
    int a = actions[r];
    float rw = rewards[r];
    float v0 = values[r];
    float nv = next_values[r];
    int dn = bytelay ? (int)((const uint8_t*)done)[r] : di[r];
    float vt1 = (t == TT - 1) ? nv : values[r + BB];

    // --- coalesced policy stage into wave-private LDS tile ---
    float* L = lpol[w];
    const float* gsrc = policy + (size_t)(t * BB + g * 64) * AA;
#pragma unroll
    for (int k = 0; k < 9; ++k) {
        int m = lane + 64 * k;
        float2 v = *(const float2*)(gsrc + 2 * m);
        int row = m / 9;
        int h = m - row * 9;
        L[(2 * h) * LDST + row]     = v.x;
        L[(2 * h + 1) * LDST + row] = v.y;
    }

    float mu = behavior[(size_t)r * AA + a];   // scattered gather, a is ready

    float ent2 = 0.f, pi = 1.f, l2pi = 0.f;
#pragma unroll
    for (int e = 0; e < AA; ++e) {
        float pe = L[e * LDST + lane];
        float le = __log2f(pe + 1e-10f);
        ent2 = fmaf(pe, le, ent2);
        if (e == a) { pi = pe; l2pi = le; }
    }
    float lpi = LN2 * l2pi;
    float c = fminf(1.0f, pi / mu);

    float disc = dn ? 0.f : 0.99f;
    float cr = fminf(1.f, fmaxf(-1.f, rw));
    float base = cr - v0;
    float dlt = c * fmaf(disc, vt1, base);
    float gg = disc * c;

    // single-timestep tuple (carry = 0)
    float vacc = dlt, P = gg;
    float sv0 = vacc * vacc;
    float sv1 = P * vacc;
    float sv2 = P * P;
    float adv = c * fmaf(disc, nv, base);
    float q = fmaf(disc, v0, base);
    float al = adv * lpi;
    float sp0 = al * fmaf(disc, vacc, q);
    float sp1 = al * disc * P;

    // stash tuple into own tile (LDS reuse; same-wave RAW handled by compiler)
    L[0 * 64 + lane] = P;
    L[1 * 64 + lane] = vacc;
    L[2 * 64 + lane] = sv1;
    L[3 * 64 + lane] = sv2;
    L[4 * 64 + lane] = sp1;

    float ent = LN2 * ent2;
    for (int off = 32; off > 0; off >>= 1) {
        ent += __shfl_down(ent, off);
        sv0 += __shfl_down(sv0, off);
        sp0 += __shfl_down(sp0, off);
    }
    if (lane == 0) { red[w][0] = ent; red[w][1] = sv0; red[w][2] = sp0; }
    __syncthreads();

    if (w == 0) {
        // compose 8 wave tuples (wave 7 = latest timestep), per column = lane
        float A  = lpol[7][0 * 64 + lane];
        float Bv = lpol[7][1 * 64 + lane];
        float s1 = lpol[7][2 * 64 + lane];
        float s2 = lpol[7][3 * 64 + lane];
        float p1 = lpol[7][4 * 64 + lane];
        float svx = 0.f, spx = 0.f;
#pragma unroll
        for (int s = WPB - 2; s >= 0; --s) {
            float Al  = lpol[s][0 * 64 + lane];
            float Bl  = lpol[s][1 * 64 + lane];
            float s1l = lpol[s][2 * 64 + lane];
            float s2l = lpol[s][3 * 64 + lane];
            float p1l = lpol[s][4 * 64 + lane];
            svx = fmaf(2.f * Bv, s1l, svx);
            svx = fmaf(Bv * Bv, s2l, svx);
            spx = fmaf(Bv, p1l, spx);
            s1 = fmaf(A, fmaf(Bv, s2l, s1l), s1);
            s2 = fmaf(A * A, s2l, s2);
            p1 = fmaf(A, p1l, p1);
            Bv = fmaf(Al, Bv, Bl);
            A  = A * Al;
        }
        int col = g * 64 + lane;
        wsf[(0 * NTBLK + tb) * BB + col] = A;
        wsf[(1 * NTBLK + tb) * BB + col] = Bv;
        wsf[(2 * NTBLK + tb) * BB + col] = s1;
        wsf[(3 * NTBLK + tb) * BB + col] = s2;
        wsf[(4 * NTBLK + tb) * BB + col] = p1;

        for (int off = 32; off > 0; off >>= 1) {
            svx += __shfl_down(svx, off);
            spx += __shfl_down(spx, off);
        }
        float eT = 0.f, vT = 0.f, pT = 0.f;
        if (lane < WPB) { eT = red[lane][0]; vT = red[lane][1]; pT = red[lane][2]; }
        for (int off = 4; off > 0; off >>= 1) {
            eT += __shfl_down(eT, off);
            vT += __shfl_down(vT, off);
            pT += __shfl_down(pT, off);
        }
        if (lane == 0) {
            part[bid * 32 + 0] = eT;
            part[bid * 32 + 1] = vT + svx;
            part[bid * 32 + 2] = pT + spx;
            __threadfence();
            // two-level completion counter (max 32-way contention)
            int last = 0;
            int gd = atomicAdd(&gcnt[bid >> 5], 1);
            if (gd == 31) {
                int rd = atomicAdd(root, 1);
                last = (rd == 31);
            }
            is_last = last;
        }
    }
    __syncthreads();
    if (!is_last) return;

    // ---- tail block: fold 32 tuples per column (4-col ILP) + final reduce ----
    int c0 = tid, c1 = tid + 512, c2 = tid + 1024, c3 = tid + 1536;
    float C0 = 0.f, C1 = 0.f, C2 = 0.f, C3 = 0.f;
    float svT = 0.f, spT = 0.f;
    for (int t2 = NTBLK - 1; t2 >= 0; --t2) {
        const float* wA = wsf + (0 * NTBLK + t2) * BB;
        const float* wB = wsf + (1 * NTBLK + t2) * BB;
        const float* w1 = wsf + (2 * NTBLK + t2) * BB;
        const float* w2 = wsf + (3 * NTBLK + t2) * BB;
        const float* wp = wsf + (4 * NTBLK + t2) * BB;
        float A0 = wA[c0], A1 = wA[c1], A2 = wA[c2], A3 = wA[c3];
        float B0 = wB[c0], B1 = wB[c1], B2 = wB[c2], B3 = wB[c3];
        float x0 = w1[c0], x1 = w1[c1], x2 = w1[c2], x3 = w1[c3];
        float y0 = w2[c0], y1 = w2[c1], y2 = w2[c2], y3 = w2[c3];
        float z0 = wp[c0], z1 = wp[c1], z2 = wp[c2], z3 = wp[c3];
        svT = fmaf(2.f * C0, x0, svT); svT = fmaf(C0 * C0, y0, svT);
        spT = fmaf(C0, z0, spT);       C0 = fmaf(A0, C0, B0);
        svT = fmaf(2.f * C1, x1, svT); svT = fmaf(C1 * C1, y1, svT);
        spT = fmaf(C1, z1, spT);       C1 = fmaf(A1, C1, B1);
        svT = fmaf(2.f * C2, x2, svT); svT = fmaf(C2 * C2, y2, svT);
        spT = fmaf(C2, z2, spT);       C2 = fmaf(A2, C2, B2);
        svT = fmaf(2.f * C3, x3, svT); svT = fmaf(C3 * C3, y3, svT);
        spT = fmaf(C3, z3, spT);       C3 = fmaf(A3, C3, B3);
    }
    float eT = 0.f, vT = svT, pT = spT;
#pragma unroll
    for (int i = 0; i < 2; ++i) {
        int j = tid + 512 * i;
        eT += part[j * 32 + 0];
        vT += part[j * 32 + 1];
        pT += part[j * 32 + 2];
    }
    for (int off = 32; off > 0; off >>= 1) {
        eT += __shfl_down(eT, off);
        vT += __shfl_down(vT, off);
        pT += __shfl_down(pT, off);
    }
    __syncthreads();   // red reuse guard
    if (lane == 0) { red[w][0] = eT; red[w][1] = vT; red[w][2] = pT; }
    __syncthreads();
    if (tid == 0) {
        double E = 0.0, V = 0.0, Pp = 0.0;
#pragma unroll
        for (int i = 0; i < WPB; ++i) {
            E += red[i][0]; V += red[i][1]; Pp += red[i][2];
        }
        // loss = (S_val - S_pol - 0.01*S_ent) / NTB
        out[0] = (float)((V - Pp - 0.01 * E) / (double)NTB);
    }
}

extern "C" void kernel_launch(void* const* d_in, const int* in_sizes, int n_in,
                              void* d_out, int out_size, void* d_ws, size_t ws_size,
                              hipStream_t stream) {
    const float* policy      = (const float*)d_in[0];
    const float* behavior    = (const float*)d_in[1];
    const float* rewards     = (const float*)d_in[2];
    const float* values      = (const float*)d_in[3];
    const float* next_values = (const float*)d_in[4];
    const int*   actions     = (const int*)d_in[5];
    const void*  done        = d_in[6];

    int*   root = (int*)d_ws;
    int*   gcnt = root + 1;
    float* part = (float*)((char*)d_ws + 256);
    float* wsf  = part + NBLK * 32;

    hipMemsetAsync(d_ws, 0, 256, stream);
    fused_k<<<NBLK, 512, 0, stream>>>(policy, behavior, rewards, values,
                                      next_values, actions, done,
                                      part, wsf, root, gcnt, (float*)d_out);
}

// Round 9
// 66.165 us; speedup vs baseline: 1.1832x; 1.1832x over previous
//
#include <hip/hip_runtime.h>
#include <stdint.h>

#define TT 256
#define BB 2048
#define AA 18
#define NTB (TT * BB)
#define WPB 4          // waves per block
#define SEGLEN 2       // timesteps per wave
#define TPB 8          // timesteps per block
#define NTBLK 32       // TT / TPB
#define NBLK 1024      // 32 col-groups * 32 time-blocks
#define LDST 65        // LDS row stride (floats), conflict-free
#define TILE (AA * LDST)
#define LN2 0.69314718055994531f

// ws: [0] root int, [4..131] gcnt[32], [256..) pe[1024],pv[1024],pp[1024],
//     fsv[32], fsp[32], then wsf[5][NTBLK][BB] (1.25 MB)

__global__ __launch_bounds__(256) void fused_k(
    const float* __restrict__ policy,
    const float* __restrict__ behavior,
    const float* __restrict__ rewards,
    const float* __restrict__ values,
    const float* __restrict__ next_values,
    const int* __restrict__ actions,
    const void* __restrict__ done,
    float* __restrict__ pe, float* __restrict__ pv, float* __restrict__ pp,
    float* __restrict__ fsv, float* __restrict__ fsp,
    float* __restrict__ wsf,
    int* __restrict__ root, int* __restrict__ gcnt,
    float* __restrict__ out)
{
    int tid = threadIdx.x;
    int lane = tid & 63;
    int w = tid >> 6;                 // wave 0..3
    int bid = blockIdx.x;
    int g = bid >> 5;                 // col-group 0..31
    int tb = bid & 31;                // time-block 0..31

    __shared__ float lpol[WPB][TILE]; // 18.3 KB -> 8 blocks/CU
    __shared__ float red[WPB][3];
    __shared__ int sflag[WPB];
    __shared__ int sfold, sfinal;

    // --- done-layout detect: 4KB scan, folded into first barrier ---
    const int* di = (const int*)done;
    int bad = 0;
#pragma unroll
    for (int k2 = 0; k2 < 4; ++k2) {
        int v = di[tid + 256 * k2];
        bad |= !(v == 0 || v == 1 || v == 0x3F800000);
    }
    bad = __any(bad);
    if (lane == 0) sflag[w] = bad;

    float* L = lpol[w];
    int b = g * 64 + lane;
    int t_hi = tb * TPB + w * SEGLEN + (SEGLEN - 1);

    float ent2 = 0.f, vacc = 0.f, P = 1.f;
    float sv0 = 0.f, sv1 = 0.f, sv2 = 0.f, sp0 = 0.f, sp1 = 0.f;
    bool bytelay = false;

#pragma unroll
    for (int i = 0; i < SEGLEN; ++i) {
        int t = t_hi - i;
        int r = t * BB + b;

        // coalesced stage: 64 rows x 18 floats into wave tile (R6 structure)
        const float* gsrc = policy + (size_t)(t * BB + g * 64) * AA;
#pragma unroll
        for (int k = 0; k < 9; ++k) {
            int m = lane + 64 * k;
            float2 v = *(const float2*)(gsrc + 2 * m);
            int row = m / 9;
            int h = m - row * 9;
            L[(2 * h) * LDST + row]     = v.x;
            L[(2 * h + 1) * LDST + row] = v.y;
        }
        __syncthreads();
        if (i == 0) bytelay = ((sflag[0] | sflag[1] | sflag[2] | sflag[3]) != 0);

        int a = actions[r];
        float pi = 1.f, l2pi = 0.f;
#pragma unroll
        for (int e = 0; e < AA; ++e) {
            float pel = L[e * LDST + lane];
            float le = __log2f(pel + 1e-10f);
            ent2 = fmaf(pel, le, ent2);
            if (e == a) { pi = pel; l2pi = le; }
        }
        float lpi = LN2 * l2pi;
        float mu = behavior[(size_t)r * AA + a];
        float c = fminf(1.0f, pi / mu);

        float rw = rewards[r];
        float v0 = values[r];
        float nv = next_values[r];
        int dn = bytelay ? (int)((const uint8_t*)done)[r] : di[r];
        float disc = dn ? 0.f : 0.99f;
        float vt1 = (t == TT - 1) ? nv : values[r + BB];

        float cr = fminf(1.f, fmaxf(-1.f, rw));
        float base = cr - v0;
        float dlt = c * fmaf(disc, vt1, base);
        float gg = disc * c;

        vacc = fmaf(gg, vacc, dlt);
        P *= gg;
        sv0 = fmaf(vacc, vacc, sv0);
        sv1 = fmaf(P, vacc, sv1);
        sv2 = fmaf(P, P, sv2);

        float adv = c * fmaf(disc, nv, base);
        float q = fmaf(disc, v0, base);
        float al = adv * lpi;
        sp0 = fmaf(al, fmaf(disc, vacc, q), sp0);
        sp1 = fmaf(al * disc, P, sp1);
        __syncthreads();
    }

    // stash wave tuple into own tile; wave-reduce carry-independent sums
    L[0 * 64 + lane] = P;
    L[1 * 64 + lane] = vacc;
    L[2 * 64 + lane] = sv1;
    L[3 * 64 + lane] = sv2;
    L[4 * 64 + lane] = sp1;
    float ent = LN2 * ent2;
    for (int off = 32; off > 0; off >>= 1) {
        ent += __shfl_down(ent, off);
        sv0 += __shfl_down(sv0, off);
        sp0 += __shfl_down(sp0, off);
    }
    if (lane == 0) { red[w][0] = ent; red[w][1] = sv0; red[w][2] = sp0; }
    __syncthreads();

    if (w == 0) {
        // compose 4 wave tuples (wave 3 = latest timesteps); column = lane
        float A  = lpol[3][0 * 64 + lane];
        float Bv = lpol[3][1 * 64 + lane];
        float s1 = lpol[3][2 * 64 + lane];
        float s2 = lpol[3][3 * 64 + lane];
        float p1 = lpol[3][4 * 64 + lane];
        float svx = 0.f, spx = 0.f;
#pragma unroll
        for (int s = WPB - 2; s >= 0; --s) {
            float Al  = lpol[s][0 * 64 + lane];
            float Bl  = lpol[s][1 * 64 + lane];
            float s1l = lpol[s][2 * 64 + lane];
            float s2l = lpol[s][3 * 64 + lane];
            float p1l = lpol[s][4 * 64 + lane];
            svx = fmaf(2.f * Bv, s1l, svx);
            svx = fmaf(Bv * Bv, s2l, svx);
            spx = fmaf(Bv, p1l, spx);
            s1 = fmaf(A, fmaf(Bv, s2l, s1l), s1);
            s2 = fmaf(A * A, s2l, s2);
            p1 = fmaf(A, p1l, p1);
            Bv = fmaf(Al, Bv, Bl);
            A  = A * Al;
        }
        int col = g * 64 + lane;
        wsf[(0 * NTBLK + tb) * BB + col] = A;
        wsf[(1 * NTBLK + tb) * BB + col] = Bv;
        wsf[(2 * NTBLK + tb) * BB + col] = s1;
        wsf[(3 * NTBLK + tb) * BB + col] = s2;
        wsf[(4 * NTBLK + tb) * BB + col] = p1;
        for (int off = 32; off > 0; off >>= 1) {
            svx += __shfl_down(svx, off);
            spx += __shfl_down(spx, off);
        }
        if (lane == 0) {
            float eT = red[0][0] + red[1][0] + red[2][0] + red[3][0];
            float vT = red[0][1] + red[1][1] + red[2][1] + red[3][1];
            float pT = red[0][2] + red[1][2] + red[2][2] + red[3][2];
            pe[bid] = eT;
            pv[bid] = vT + svx;
            pp[bid] = pT + spx;
            __threadfence();
            int gd = atomicAdd(&gcnt[g], 1);
            sfold = (gd == 31) ? 1 : 0;
        }
    }
    __syncthreads();
    if (!sfold) return;

    // ---- folder (one block per col-group, overlapped with main phase) ----
    __threadfence();   // acquire wsf written by the other 31 blocks
    // quarter-parallel fold: col = lane, quarter q = w covers tb2 in [q*8,q*8+8)
    {
        float a_ = 1.f, b_ = 0.f;
        float al_ = 0.f, be_ = 0.f, ga_ = 0.f, de_ = 0.f, ep_ = 0.f;
        int col = g * 64 + lane;
#pragma unroll
        for (int s = 7; s >= 0; --s) {
            int tb2 = w * 8 + s;
            float A  = wsf[(0 * NTBLK + tb2) * BB + col];
            float Bv = wsf[(1 * NTBLK + tb2) * BB + col];
            float s1 = wsf[(2 * NTBLK + tb2) * BB + col];
            float s2 = wsf[(3 * NTBLK + tb2) * BB + col];
            float p1 = wsf[(4 * NTBLK + tb2) * BB + col];
            ga_ = fmaf(a_ * a_, s2, ga_);
            be_ = fmaf(a_, fmaf(b_, s2, s1), be_);
            al_ = fmaf(b_, fmaf(b_, s2, 2.f * s1), al_);
            ep_ = fmaf(a_, p1, ep_);
            de_ = fmaf(b_, p1, de_);
            b_ = fmaf(A, b_, Bv);
            a_ *= A;
        }
        float* F = (float*)lpol;          // reuse tiles (main phase done)
        float* Fq = F + (w * 64 + lane) * 9;   // stride 9: 2-way banks
        Fq[0] = a_; Fq[1] = b_; Fq[2] = al_; Fq[3] = be_; Fq[4] = ga_;
        Fq[5] = de_; Fq[6] = ep_;
    }
    __syncthreads();
    float svT = 0.f, spT = 0.f;
    if (tid < 64) {
        const float* F = (const float*)lpol;
        float C = 0.f;
#pragma unroll
        for (int q2 = 3; q2 >= 0; --q2) {
            const float* Fc = F + (q2 * 64 + tid) * 9;
            float aa = Fc[0], bb = Fc[1], aal = Fc[2], bbe = Fc[3];
            float gga = Fc[4], dde = Fc[5], eep = Fc[6];
            svT += aal + 2.f * bbe * C + gga * C * C;
            spT += dde + eep * C;
            C = fmaf(aa, C, bb);
        }
        for (int off = 32; off > 0; off >>= 1) {
            svT += __shfl_down(svT, off);
            spT += __shfl_down(spT, off);
        }
    }
    if (tid == 0) {
        fsv[g] = svT;
        fsp[g] = spT;
        __threadfence();
        int rd = atomicAdd(root, 1);
        sfinal = (rd == 31) ? 1 : 0;
    }
    __syncthreads();
    if (!sfinal) return;

    // ---- final reduce (last folder block): coalesced SoA partials ----
    __threadfence();
    float e = 0.f, vv = 0.f, ppp = 0.f;
#pragma unroll
    for (int k2 = 0; k2 < 4; ++k2) {
        int j = tid + 256 * k2;
        e   += pe[j];
        vv  += pv[j];
        ppp += pp[j];
    }
    if (tid < 32) { vv += fsv[tid]; ppp += fsp[tid]; }
    for (int off = 32; off > 0; off >>= 1) {
        e   += __shfl_down(e, off);
        vv  += __shfl_down(vv, off);
        ppp += __shfl_down(ppp, off);
    }
    if (lane == 0) { red[w][0] = e; red[w][1] = vv; red[w][2] = ppp; }
    __syncthreads();
    if (tid == 0) {
        double E = 0.0, V = 0.0, Pp = 0.0;
#pragma unroll
        for (int i = 0; i < WPB; ++i) {
            E += red[i][0]; V += red[i][1]; Pp += red[i][2];
        }
        // loss = (S_val - S_pol - 0.01*S_ent) / NTB
        out[0] = (float)((V - Pp - 0.01 * E) / (double)NTB);
    }
}

extern "C" void kernel_launch(void* const* d_in, const int* in_sizes, int n_in,
                              void* d_out, int out_size, void* d_ws, size_t ws_size,
                              hipStream_t stream) {
    const float* policy      = (const float*)d_in[0];
    const float* behavior    = (const float*)d_in[1];
    const float* rewards     = (const float*)d_in[2];
    const float* values      = (const float*)d_in[3];
    const float* next_values = (const float*)d_in[4];
    const int*   actions     = (const int*)d_in[5];
    const void*  done        = d_in[6];

    int*   root = (int*)d_ws;
    int*   gcnt = root + 1;
    float* pe   = (float*)((char*)d_ws + 256);
    float* pv   = pe + NBLK;
    float* pp   = pv + NBLK;
    float* fsv  = pp + NBLK;
    float* fsp  = fsv + 32;
    float* wsf  = fsp + 32;

    hipMemsetAsync(d_ws, 0, 256, stream);
    fused_k<<<NBLK, 256, 0, stream>>>(policy, behavior, rewards, values,
                                      next_values, actions, done,
                                      pe, pv, pp, fsv, fsp, wsf,
                                      root, gcnt, (float*)d_out);
}

// Round 10
// 27.194 us; speedup vs baseline: 2.8788x; 2.4331x over previous
//
#include <hip/hip_runtime.h>
#include <stdint.h>

#define TT 256
#define BB 2048
#define AA 18
#define NTB (TT * BB)
#define WPB 4          // waves per block
#define SEGLEN 2       // timesteps per wave
#define TPB 8          // timesteps per block
#define NTBLK 32       // TT / TPB
#define NBLK 1024      // 32 col-groups * 32 time-blocks
#define LDST 65        // LDS row stride (floats), conflict-free
#define TILE (AA * LDST)
#define LN2 0.69314718055994531f

// ws: pe[NBLK], pv[NBLK], pp[NBLK], fsv[8], fsp[8], wsf[5][NTBLK][BB] (1.25 MB)
// No atomics, no fences, no counters: kernel boundaries do all synchronization.

__global__ __launch_bounds__(256) void main_k(
    const float* __restrict__ policy,
    const float* __restrict__ behavior,
    const float* __restrict__ rewards,
    const float* __restrict__ values,
    const float* __restrict__ next_values,
    const int* __restrict__ actions,
    const void* __restrict__ done,
    float* __restrict__ pe, float* __restrict__ pv, float* __restrict__ pp,
    float* __restrict__ wsf)
{
    int tid = threadIdx.x;
    int lane = tid & 63;
    int w = tid >> 6;                 // wave 0..3
    int bid = blockIdx.x;
    int g = bid >> 5;                 // col-group 0..31
    int tb = bid & 31;                // time-block 0..31

    __shared__ float lpol[WPB][TILE]; // 18.3 KB, wave-private -> 8 blocks/CU
    __shared__ float red[WPB][3];

    // per-wave done-layout detection (4KB scan, wave-uniform, no barrier)
    const int* di = (const int*)done;
    int bad = 0;
#pragma unroll
    for (int i = 0; i < 16; ++i) {
        int v = di[lane + 64 * i];
        bad |= !(v == 0 || v == 1 || v == 0x3F800000);
    }
    bool bytelay = (__any(bad) != 0);
    const uint8_t* d8 = (const uint8_t*)done;

    float* L = lpol[w];
    int b = g * 64 + lane;
    int tA = tb * TPB + w * SEGLEN + 1;   // later step, processed first
    int tB = tA - 1;
    int rA = tA * BB + b, rB = tB * BB + b;

    // prefetch ALL scalar inputs + both gathers up front (latency overlaps staging)
    int aA = actions[rA], aB = actions[rB];
    float muA = behavior[(size_t)rA * AA + aA];
    float muB = behavior[(size_t)rB * AA + aB];
    float rwA = rewards[rA], rwB = rewards[rB];
    float v0A = values[rA],  v0B = values[rB];
    float nvA = next_values[rA], nvB = next_values[rB];
    int dnA = bytelay ? (int)d8[rA] : di[rA];
    int dnB = bytelay ? (int)d8[rB] : di[rB];
    float vtA = (tA == TT - 1) ? nvA : values[rA + BB];
    float vtB = v0A;                      // values[tB+1] == values[tA]

    float ent2 = 0.f, vacc = 0.f, P = 1.f;
    float sv0 = 0.f, sv1 = 0.f, sv2 = 0.f, sp0 = 0.f, sp1 = 0.f;

    auto step = [&](int t, int a, float mu, float rw, float v0, float nv,
                    int dn, float vt1) {
        // coalesced stage: 64 rows x 18 floats into wave-private tile, NO barrier
        const float* gsrc = policy + (size_t)(t * BB + g * 64) * AA;
#pragma unroll
        for (int k = 0; k < 9; ++k) {
            int m = lane + 64 * k;
            float2 v = *(const float2*)(gsrc + 2 * m);
            int row = m / 9;
            int h = m - row * 9;
            L[(2 * h) * LDST + row]     = v.x;
            L[(2 * h + 1) * LDST + row] = v.y;
        }
        float pi = 1.f, l2pi = 0.f;
#pragma unroll
        for (int e = 0; e < AA; ++e) {
            float pel = L[e * LDST + lane];
            float le = __log2f(pel + 1e-10f);
            ent2 = fmaf(pel, le, ent2);
            if (e == a) { pi = pel; l2pi = le; }
        }
        float lpi = LN2 * l2pi;
        float c = fminf(1.0f, pi / mu);
        float disc = dn ? 0.f : 0.99f;
        float cr = fminf(1.f, fmaxf(-1.f, rw));
        float base = cr - v0;
        float dlt = c * fmaf(disc, vt1, base);
        float gg = disc * c;
        vacc = fmaf(gg, vacc, dlt);          // local value (zero carry)
        P *= gg;                             // carry coefficient
        sv0 = fmaf(vacc, vacc, sv0);
        sv1 = fmaf(P, vacc, sv1);
        sv2 = fmaf(P, P, sv2);
        float adv = c * fmaf(disc, nv, base);
        float q = fmaf(disc, v0, base);
        float al = adv * lpi;
        sp0 = fmaf(al, fmaf(disc, vacc, q), sp0);
        sp1 = fmaf(al * disc, P, sp1);
    };

    step(tA, aA, muA, rwA, v0A, nvA, dnA, vtA);
    step(tB, aB, muB, rwB, v0B, nvB, dnB, vtB);

    // stash wave tuple into own tile; wave-reduce carry-independent sums
    L[0 * 64 + lane] = P;
    L[1 * 64 + lane] = vacc;
    L[2 * 64 + lane] = sv1;
    L[3 * 64 + lane] = sv2;
    L[4 * 64 + lane] = sp1;
    float ent = LN2 * ent2;
    for (int off = 32; off > 0; off >>= 1) {
        ent += __shfl_down(ent, off);
        sv0 += __shfl_down(sv0, off);
        sp0 += __shfl_down(sp0, off);
    }
    if (lane == 0) { red[w][0] = ent; red[w][1] = sv0; red[w][2] = sp0; }
    __syncthreads();   // the ONLY block barrier

    if (w == 0) {
        // compose 4 wave tuples (wave 3 = latest timesteps); column = lane
        float A  = lpol[3][0 * 64 + lane];
        float Bv = lpol[3][1 * 64 + lane];
        float s1 = lpol[3][2 * 64 + lane];
        float s2 = lpol[3][3 * 64 + lane];
        float p1 = lpol[3][4 * 64 + lane];
        float svx = 0.f, spx = 0.f;
#pragma unroll
        for (int s = WPB - 2; s >= 0; --s) {
            float Al  = lpol[s][0 * 64 + lane];
            float Bl  = lpol[s][1 * 64 + lane];
            float s1l = lpol[s][2 * 64 + lane];
            float s2l = lpol[s][3 * 64 + lane];
            float p1l = lpol[s][4 * 64 + lane];
            svx = fmaf(2.f * Bv, s1l, svx);
            svx = fmaf(Bv * Bv, s2l, svx);
            spx = fmaf(Bv, p1l, spx);
            s1 = fmaf(A, fmaf(Bv, s2l, s1l), s1);
            s2 = fmaf(A * A, s2l, s2);
            p1 = fmaf(A, p1l, p1);
            Bv = fmaf(Al, Bv, Bl);
            A  = A * Al;
        }
        int col = g * 64 + lane;
        wsf[(0 * NTBLK + tb) * BB + col] = A;
        wsf[(1 * NTBLK + tb) * BB + col] = Bv;
        wsf[(2 * NTBLK + tb) * BB + col] = s1;
        wsf[(3 * NTBLK + tb) * BB + col] = s2;
        wsf[(4 * NTBLK + tb) * BB + col] = p1;
        for (int off = 32; off > 0; off >>= 1) {
            svx += __shfl_down(svx, off);
            spx += __shfl_down(spx, off);
        }
        if (lane == 0) {
            pe[bid] = red[0][0] + red[1][0] + red[2][0] + red[3][0];
            pv[bid] = red[0][1] + red[1][1] + red[2][1] + red[3][1] + svx;
            pp[bid] = red[0][2] + red[1][2] + red[2][2] + red[3][2] + spx;
        }
    }
}

// Fold 32 composed tuples per column. 8 blocks x 256 threads, thread = column;
// SoA layout -> fully coalesced reads.
__global__ __launch_bounds__(256) void fold_k(
    const float* __restrict__ wsf,
    float* __restrict__ fsv, float* __restrict__ fsp)
{
    int tid = threadIdx.x;
    int col = blockIdx.x * 256 + tid;     // 0..2047
    float C = 0.f, svT = 0.f, spT = 0.f;
#pragma unroll 8
    for (int tb2 = NTBLK - 1; tb2 >= 0; --tb2) {
        float A  = wsf[(0 * NTBLK + tb2) * BB + col];
        float Bv = wsf[(1 * NTBLK + tb2) * BB + col];
        float s1 = wsf[(2 * NTBLK + tb2) * BB + col];
        float s2 = wsf[(3 * NTBLK + tb2) * BB + col];
        float p1 = wsf[(4 * NTBLK + tb2) * BB + col];
        svT = fmaf(2.f * C, s1, svT);
        svT = fmaf(C * C, s2, svT);
        spT = fmaf(C, p1, spT);
        C = fmaf(A, C, Bv);
    }
    for (int off = 32; off > 0; off >>= 1) {
        svT += __shfl_down(svT, off);
        spT += __shfl_down(spT, off);
    }
    __shared__ float s1r[4], s2r[4];
    int lane = tid & 63, w = tid >> 6;
    if (lane == 0) { s1r[w] = svT; s2r[w] = spT; }
    __syncthreads();
    if (tid == 0) {
        fsv[blockIdx.x] = s1r[0] + s1r[1] + s1r[2] + s1r[3];
        fsp[blockIdx.x] = s2r[0] + s2r[1] + s2r[2] + s2r[3];
    }
}

__global__ __launch_bounds__(256) void final_k(
    const float* __restrict__ pe, const float* __restrict__ pv,
    const float* __restrict__ pp, const float* __restrict__ fsv,
    const float* __restrict__ fsp, float* __restrict__ out)
{
    int tid = threadIdx.x;
    float e = 0.f, v = 0.f, p = 0.f;
#pragma unroll
    for (int i = 0; i < NBLK / 256; ++i) {
        int j = tid + 256 * i;
        e += pe[j];
        v += pv[j];
        p += pp[j];
    }
    if (tid < 8) { v += fsv[tid]; p += fsp[tid]; }
    for (int off = 32; off > 0; off >>= 1) {
        e += __shfl_down(e, off);
        v += __shfl_down(v, off);
        p += __shfl_down(p, off);
    }
    __shared__ float s0[4], s1[4], s2[4];
    int lane = tid & 63, w = tid >> 6;
    if (lane == 0) { s0[w] = e; s1[w] = v; s2[w] = p; }
    __syncthreads();
    if (tid == 0) {
        double E  = (double)s0[0] + s0[1] + s0[2] + s0[3];
        double V  = (double)s1[0] + s1[1] + s1[2] + s1[3];
        double Pp = (double)s2[0] + s2[1] + s2[2] + s2[3];
        // loss = (S_val - S_pol - 0.01*S_ent) / NTB
        out[0] = (float)((V - Pp - 0.01 * E) / (double)NTB);
    }
}

extern "C" void kernel_launch(void* const* d_in, const int* in_sizes, int n_in,
                              void* d_out, int out_size, void* d_ws, size_t ws_size,
                              hipStream_t stream) {
    const float* policy      = (const float*)d_in[0];
    const float* behavior    = (const float*)d_in[1];
    const float* rewards     = (const float*)d_in[2];
    const float* values      = (const float*)d_in[3];
    const float* next_values = (const float*)d_in[4];
    const int*   actions     = (const int*)d_in[5];
    const void*  done        = d_in[6];

    float* pe  = (float*)d_ws;
    float* pv  = pe + NBLK;
    float* pp  = pv + NBLK;
    float* fsv = pp + NBLK;
    float* fsp = fsv + 8;
    float* wsf = fsp + 8;

    main_k<<<NBLK, 256, 0, stream>>>(policy, behavior, rewards, values,
                                     next_values, actions, done,
                                     pe, pv, pp, wsf);
    fold_k<<<8, 256, 0, stream>>>(wsf, fsv, fsp);
    final_k<<<1, 256, 0, stream>>>(pe, pv, pp, fsv, fsp, (float*)d_out);
}